// Round 2
// baseline (347.250 us; speedup 1.0000x reference)
//
#include <hip/hip_runtime.h>

#define NS 16
#define N_ATOMS 2000
#define NB 2000
#define NA 4000
#define NV 400000
#define NT 6000
#define NI 1000

#define OUT_S 819001
#define OFF_EB 0
#define OFF_EA 2000
#define OFF_EUB 6000
#define OFF_EV 6001
#define OFF_EC 406001
#define OFF_ET 806001
#define OFF_EI 812001
#define OFF_F 813001

#define CHARGE_TENTH 1.8222615f

// ---------------------------------------------------------------------------
// Zero the Force region + E_ub slot for every sample.
__global__ void init_kernel(float* __restrict__ out) {
    int idx = blockIdx.x * blockDim.x + threadIdx.x;
    const int per_s = N_ATOMS * 3 + 1;
    const int total = NS * per_s;
    if (idx >= total) return;
    int s = idx / per_s;
    int r = idx - s * per_s;
    if (r == 0)
        out[(size_t)s * OUT_S + OFF_EUB] = 0.0f;
    else
        out[(size_t)s * OUT_S + OFF_F + (r - 1)] = 0.0f;
}

// ---------------------------------------------------------------------------
// Precompute per-v (sample-independent) vdw/charge params: removes the
// dependent gather chain from the 16x-replayed main kernel.
// ws[v] = { sig6, eps, cc, bitcast(b0 | b1<<16) }
__global__ __launch_bounds__(256) void prep_kernel(
    const float* __restrict__ v14,
    const float* __restrict__ q14,
    const float* __restrict__ pv,
    const float* __restrict__ pc,
    const int*   __restrict__ nb,
    const int*   __restrict__ nbi,
    float4* __restrict__ ws)
{
    int v = blockIdx.x * blockDim.x + threadIdx.x;
    if (v >= NV) return;
    int i = nb[v];
    int j = nb[NV + v];
    float2 pvi = ((const float2*)pv)[i];
    float2 pvj = ((const float2*)pv)[j];
    float sigma = pvi.x + pvj.x;
    float sig2  = sigma * sigma;
    float sig6  = sig2 * sig2 * sig2;
    float eps   = pvi.y * pvj.y * 0.01f * v14[v];
    float cc    = (CHARGE_TENTH * CHARGE_TENTH) * pc[i] * pc[j] * q14[v];
    int2 aa = ((const int2*)nbi)[v];
    unsigned int packed = (unsigned int)aa.x | ((unsigned int)aa.y << 16);
    float4 w;
    w.x = sig6; w.y = eps; w.z = cc; w.w = __uint_as_float(packed);
    ws[v] = w;
}

// ---------------------------------------------------------------------------
// Bond + angle + torsion + imptors: energies direct, forces via global atomics.
__global__ __launch_bounds__(256) void bonded_kernel(
    const float* __restrict__ lb,
    const float* __restrict__ th,
    const float* __restrict__ sc,
    const float* __restrict__ c2i,
    const float* __restrict__ pb,
    const float* __restrict__ pa,
    const float* __restrict__ pt,
    const float* __restrict__ pim,
    const float* __restrict__ dlb,
    const float* __restrict__ dth,
    const float* __restrict__ dtt,
    const float* __restrict__ dc2,
    const int*   __restrict__ bidx,
    const int*   __restrict__ aidx,
    const int*   __restrict__ tidx,
    const int*   __restrict__ iidx,
    float* __restrict__ out)
{
    int t = blockIdx.x * blockDim.x + threadIdx.x;
    int s = blockIdx.y;
    float* F = out + (size_t)s * OUT_S + OFF_F;

    if (t < NB) {
        int b = t;
        float2 p = ((const float2*)pb)[b];
        float K  = p.x * 100.0f;
        float d  = lb[s * NB + b] - p.y;
        out[(size_t)s * OUT_S + OFF_EB + b] = K * d * d;
        float g = 2.0f * K * d;
        const float* dd = dlb + ((size_t)s * NB + b) * 6;
        int a0 = bidx[2 * b] * 3, a1 = bidx[2 * b + 1] * 3;
        float d0 = dd[0], d1 = dd[1], d2 = dd[2], d3 = dd[3], d4 = dd[4], d5 = dd[5];
        atomicAdd(&F[a0 + 0], d0 * g);
        atomicAdd(&F[a0 + 1], d1 * g);
        atomicAdd(&F[a0 + 2], d2 * g);
        atomicAdd(&F[a1 + 0], d3 * g);
        atomicAdd(&F[a1 + 1], d4 * g);
        atomicAdd(&F[a1 + 2], d5 * g);
    } else if (t < NB + NA) {
        int a = t - NB;
        float2 p = ((const float2*)pa)[a];
        float Ka  = p.x * 10.0f;
        float da  = th[s * NA + a] - p.y * 0.31415926535f;
        out[(size_t)s * OUT_S + OFF_EA + a] = Ka * da * da;
        float g = 2.0f * Ka * da;
        const float* dd = dth + ((size_t)s * NA + a) * 9;
        int a0 = aidx[3 * a] * 3, a1 = aidx[3 * a + 1] * 3, a2 = aidx[3 * a + 2] * 3;
        #pragma unroll
        for (int c = 0; c < 3; ++c) atomicAdd(&F[a0 + c], dd[c] * g);
        #pragma unroll
        for (int c = 0; c < 3; ++c) atomicAdd(&F[a1 + c], dd[3 + c] * g);
        #pragma unroll
        for (int c = 0; c < 3; ++c) atomicAdd(&F[a2 + c], dd[6 + c] * g);
    } else if (t < NB + NA + NT) {
        int tt = t - (NB + NA);
        const float* s8 = sc + ((size_t)s * NT + tt) * 8;
        const float* p4 = pt + (size_t)tt * 4;
        float E = 0.0f, Sf = 0.0f;
        #pragma unroll
        for (int n = 0; n < 4; ++n) {
            float pn = p4[n];
            E  += s8[2 * n + 1] * pn;
            Sf += s8[2 * n]     * pn * (float)(n + 1);
        }
        out[(size_t)s * OUT_S + OFF_ET + tt] = E;
        float g = -Sf;
        const float* dd = dtt + ((size_t)s * NT + tt) * 12;
        #pragma unroll
        for (int p = 0; p < 4; ++p) {
            int at = tidx[4 * tt + p] * 3;
            atomicAdd(&F[at + 0], dd[3 * p + 0] * g);
            atomicAdd(&F[at + 1], dd[3 * p + 1] * g);
            atomicAdd(&F[at + 2], dd[3 * p + 2] * g);
        }
    } else if (t < NB + NA + NT + NI) {
        int ii = t - (NB + NA + NT);
        float ki = pim[ii];
        out[(size_t)s * OUT_S + OFF_EI + ii] = ki * (1.0f - c2i[s * NI + ii]);
        float g = -ki;
        const float* dd = dc2 + ((size_t)s * NI + ii) * 12;
        #pragma unroll
        for (int p = 0; p < 4; ++p) {
            int at = iidx[4 * ii + p] * 3;
            atomicAdd(&F[at + 0], dd[3 * p + 0] * g);
            atomicAdd(&F[at + 1], dd[3 * p + 1] * g);
            atomicAdd(&F[at + 2], dd[3 * p + 2] * g);
        }
    }
}

// ---------------------------------------------------------------------------
// vdw + charge main: pure streaming (no gathers), 4-way ILP, LDS accumulate.
#define NCHUNK 64
#define VC (NV / NCHUNK)   // 6250
#define VBLK 512

__global__ __launch_bounds__(VBLK, 8) void vdw_kernel(
    const float*  __restrict__ lv,
    const float*  __restrict__ dlv,
    const float4* __restrict__ ws,
    float* __restrict__ out)
{
    __shared__ float fbuf[N_ATOMS * 3];
    int tid   = threadIdx.x;
    int s     = blockIdx.x;
    int chunk = blockIdx.y;

    for (int k = tid; k < N_ATOMS * 3; k += VBLK) fbuf[k] = 0.0f;
    __syncthreads();

    const int v0   = chunk * VC;
    const int vend = v0 + VC;
    const float* lvs = lv + (size_t)s * NV;
    float* outE = out + (size_t)s * OUT_S;
    const float* dbase = dlv + (size_t)s * NV * 6;

    for (int base = v0; base < vend; base += 4 * VBLK) {
        float4 w[4];
        float  r[4];
        float2 d0[4], d1[4], d2[4];
        int    vv[4];
        bool   act[4];
        #pragma unroll
        for (int k = 0; k < 4; ++k) {
            vv[k]  = base + tid + k * VBLK;
            act[k] = vv[k] < vend;
            if (act[k]) {
                w[k] = ws[vv[k]];
                r[k] = lvs[vv[k]];
                const float2* dd = (const float2*)(dbase + (size_t)vv[k] * 6);
                d0[k] = dd[0]; d1[k] = dd[1]; d2[k] = dd[2];
            }
        }
        #pragma unroll
        for (int k = 0; k < 4; ++k) {
            if (!act[k]) continue;
            int v = vv[k];
            float rinv  = __builtin_amdgcn_rcpf(r[k]);
            float r2inv = rinv * rinv;
            float r6inv = r2inv * r2inv * r2inv;
            float t     = w[k].x * r6inv;
            float eps   = w[k].y;
            float cc    = w[k].z;
            float Ev    = eps * (t * t - 2.0f * t);
            float Ec    = cc * rinv;
            float fs    = 12.0f * eps * t * (1.0f - t) * rinv - cc * r2inv;
            outE[OFF_EV + v] = Ev;
            outE[OFF_EC + v] = Ec;
            unsigned int p = __float_as_uint(w[k].w);
            int b0 = (int)(p & 0xffffu) * 3;
            int b1 = (int)(p >> 16) * 3;
            atomicAdd(&fbuf[b0 + 0], d0[k].x * fs);
            atomicAdd(&fbuf[b0 + 1], d0[k].y * fs);
            atomicAdd(&fbuf[b0 + 2], d1[k].x * fs);
            atomicAdd(&fbuf[b1 + 0], d1[k].y * fs);
            atomicAdd(&fbuf[b1 + 1], d2[k].x * fs);
            atomicAdd(&fbuf[b1 + 2], d2[k].y * fs);
        }
    }
    __syncthreads();

    float* F = outE + OFF_F;
    for (int k = tid; k < N_ATOMS * 3; k += VBLK) {
        float val = fbuf[k];
        if (val != 0.0f) atomicAdd(&F[k], val);
    }
}

// ---------------------------------------------------------------------------
extern "C" void kernel_launch(void* const* d_in, const int* in_sizes, int n_in,
                              void* d_out, int out_size, void* d_ws, size_t ws_size,
                              hipStream_t stream) {
    const float* lb  = (const float*)d_in[0];
    const float* th  = (const float*)d_in[1];
    const float* lv  = (const float*)d_in[2];
    const float* sc  = (const float*)d_in[3];
    const float* c2i = (const float*)d_in[4];
    const float* v14 = (const float*)d_in[5];
    const float* q14 = (const float*)d_in[6];
    const float* pb  = (const float*)d_in[7];
    const float* pa  = (const float*)d_in[8];
    const float* pv  = (const float*)d_in[9];
    const float* pc  = (const float*)d_in[10];
    const float* pt  = (const float*)d_in[11];
    const float* pim = (const float*)d_in[12];
    const float* dlb = (const float*)d_in[13];
    const float* dth = (const float*)d_in[14];
    const float* dlv = (const float*)d_in[15];
    const float* dtt = (const float*)d_in[16];
    const float* dc2 = (const float*)d_in[17];
    const int* nb    = (const int*)d_in[18];
    const int* bidx  = (const int*)d_in[19];
    const int* aidx  = (const int*)d_in[20];
    const int* nbi   = (const int*)d_in[21];
    const int* tidx  = (const int*)d_in[22];
    const int* iidx  = (const int*)d_in[23];
    float* out = (float*)d_out;
    float4* ws = (float4*)d_ws;

    // 1) zero Force + E_ub
    {
        int total = NS * (N_ATOMS * 3 + 1);
        init_kernel<<<(total + 255) / 256, 256, 0, stream>>>(out);
    }
    // 2) per-v vdw/charge param precompute (sample-independent)
    {
        prep_kernel<<<(NV + 255) / 256, 256, 0, stream>>>(v14, q14, pv, pc, nb, nbi, ws);
    }
    // 3) bonded terms
    {
        dim3 grid((NB + NA + NT + NI + 255) / 256, NS);
        bonded_kernel<<<grid, 256, 0, stream>>>(lb, th, sc, c2i, pb, pa, pt, pim,
                                                dlb, dth, dtt, dc2,
                                                bidx, aidx, tidx, iidx, out);
    }
    // 4) vdw + charge streaming
    {
        dim3 grid(NS, NCHUNK);
        vdw_kernel<<<grid, VBLK, 0, stream>>>(lv, dlv, ws, out);
    }
}

// Round 4
// 178.143 us; speedup vs baseline: 1.9493x; 1.9493x over previous
//
#include <hip/hip_runtime.h>

#define NS 16
#define N_ATOMS 2000
#define NB 2000
#define NA 4000
#define NV 400000
#define NT 6000
#define NI 1000

#define OUT_S 819001
#define OFF_EB 0
#define OFF_EA 2000
#define OFF_EUB 6000
#define OFF_EV 6001
#define OFF_EC 406001
#define OFF_ET 806001
#define OFF_EI 812001
#define OFF_F 813001

#define CHARGE_TENTH 1.8222615f

#define NBOND_TOT (NB + NA + NT + NI)   // 13000

typedef __fp16 h2 __attribute__((ext_vector_type(2)));

// ---------------------------------------------------------------------------
// Kernel 1: zero Force/E_ub  +  per-v vdw/charge param precompute.
__global__ __launch_bounds__(512) void init_prep_kernel(
    const float* __restrict__ v14,
    const float* __restrict__ q14,
    const float* __restrict__ pv,
    const float* __restrict__ pc,
    const int*   __restrict__ nb,
    const int*   __restrict__ nbi,
    float4* __restrict__ ws,
    float* __restrict__ out)
{
    int idx = blockIdx.x * blockDim.x + threadIdx.x;

    // init part
    const int per_s = N_ATOMS * 3 + 1;
    if (idx < NS * per_s) {
        int s = idx / per_s;
        int r = idx - s * per_s;
        if (r == 0)
            out[(size_t)s * OUT_S + OFF_EUB] = 0.0f;
        else
            out[(size_t)s * OUT_S + OFF_F + (r - 1)] = 0.0f;
    }

    // prep part
    if (idx < NV) {
        int v = idx;
        int i = nb[v];
        int j = nb[NV + v];
        float2 pvi = ((const float2*)pv)[i];
        float2 pvj = ((const float2*)pv)[j];
        float sigma = pvi.x + pvj.x;
        float sig2  = sigma * sigma;
        float sig6  = sig2 * sig2 * sig2;
        float eps   = pvi.y * pvj.y * 0.01f * v14[v];
        float cc    = (CHARGE_TENTH * CHARGE_TENTH) * pc[i] * pc[j] * q14[v];
        int2 aa = ((const int2*)nbi)[v];
        unsigned int packed = (unsigned int)aa.x | ((unsigned int)aa.y << 16);
        float4 w;
        w.x = sig6; w.y = eps; w.z = cc; w.w = __uint_as_float(packed);
        ws[v] = w;
    }
}

// ---------------------------------------------------------------------------
// Kernel 2: fat kernel — vdw+charge (blockIdx.y < NCHUNK) and bonded terms
// (blockIdx.y >= NCHUNK) run concurrently on the GPU.
#define NCHUNK 32
#define VC (NV / NCHUNK)        // 12500
#define PPC (VC / 2)            // 6250 pairs per chunk
#define VBLK 512
#define VITER ((PPC + VBLK - 1) / VBLK)   // 13
#define NBBLK ((NBOND_TOT + VBLK - 1) / VBLK)  // 26

__device__ __forceinline__ void lds_pk_add(unsigned* base, int idx, float x, float y) {
    h2 ph = __builtin_amdgcn_cvt_pkrtz(x, y);
    unsigned pk = __builtin_bit_cast(unsigned, ph);
    unsigned addr = (unsigned)(uintptr_t)(&base[idx]);   // low 32 bits of generic LDS ptr = DS byte offset
    asm volatile("ds_pk_add_f16 %0, %1" : : "v"(addr), "v"(pk) : "memory");
}

__global__ __launch_bounds__(VBLK, 4) void fused_kernel(
    const float*  __restrict__ lv,
    const float*  __restrict__ dlv,
    const float4* __restrict__ ws,
    const float* __restrict__ lb,
    const float* __restrict__ th,
    const float* __restrict__ sc,
    const float* __restrict__ c2i,
    const float* __restrict__ pb,
    const float* __restrict__ pa,
    const float* __restrict__ pt,
    const float* __restrict__ pim,
    const float* __restrict__ dlb,
    const float* __restrict__ dth,
    const float* __restrict__ dtt,
    const float* __restrict__ dc2,
    const int*   __restrict__ bidx,
    const int*   __restrict__ aidx,
    const int*   __restrict__ tidx,
    const int*   __restrict__ iidx,
    float* __restrict__ out)
{
    __shared__ unsigned fxy[N_ATOMS];   // packed f16 (x,y) accumulators
    __shared__ float    fz[N_ATOMS];    // f32 z accumulators

    int tid = threadIdx.x;
    int s   = blockIdx.x;
    float* outE = out + (size_t)s * OUT_S;
    float* F = outE + OFF_F;

    if (blockIdx.y >= NCHUNK) {
        // ---------------- bonded path ----------------
        int t = (blockIdx.y - NCHUNK) * VBLK + tid;
        if (t < NB) {
            int b = t;
            float2 p = ((const float2*)pb)[b];
            float K  = p.x * 100.0f;
            float d  = lb[s * NB + b] - p.y;
            outE[OFF_EB + b] = K * d * d;
            float g = 2.0f * K * d;
            const float2* dd = (const float2*)(dlb + ((size_t)s * NB + b) * 6);
            float2 d0 = dd[0], d1 = dd[1], d2 = dd[2];
            int a0 = bidx[2 * b] * 3, a1 = bidx[2 * b + 1] * 3;
            atomicAdd(&F[a0 + 0], d0.x * g);
            atomicAdd(&F[a0 + 1], d0.y * g);
            atomicAdd(&F[a0 + 2], d1.x * g);
            atomicAdd(&F[a1 + 0], d1.y * g);
            atomicAdd(&F[a1 + 1], d2.x * g);
            atomicAdd(&F[a1 + 2], d2.y * g);
        } else if (t < NB + NA) {
            int a = t - NB;
            float2 p = ((const float2*)pa)[a];
            float Ka  = p.x * 10.0f;
            float da  = th[s * NA + a] - p.y * 0.31415926535f;
            outE[OFF_EA + a] = Ka * da * da;
            float g = 2.0f * Ka * da;
            const float* dd = dth + ((size_t)s * NA + a) * 9;
            int a0 = aidx[3 * a] * 3, a1 = aidx[3 * a + 1] * 3, a2 = aidx[3 * a + 2] * 3;
            #pragma unroll
            for (int c = 0; c < 3; ++c) atomicAdd(&F[a0 + c], dd[c] * g);
            #pragma unroll
            for (int c = 0; c < 3; ++c) atomicAdd(&F[a1 + c], dd[3 + c] * g);
            #pragma unroll
            for (int c = 0; c < 3; ++c) atomicAdd(&F[a2 + c], dd[6 + c] * g);
        } else if (t < NB + NA + NT) {
            int tt = t - (NB + NA);
            const float4* s8 = (const float4*)(sc + ((size_t)s * NT + tt) * 8);
            float4 sA = s8[0], sB = s8[1];
            float4 p4 = ((const float4*)pt)[tt];
            float E  = sA.y * p4.x + sA.w * p4.y + sB.y * p4.z + sB.w * p4.w;
            float Sf = sA.x * p4.x + sA.z * p4.y * 2.0f + sB.x * p4.z * 3.0f + sB.z * p4.w * 4.0f;
            outE[OFF_ET + tt] = E;
            float g = -Sf;
            const float4* dd = (const float4*)(dtt + ((size_t)s * NT + tt) * 12);
            float4 dA = dd[0], dB = dd[1], dC = dd[2];
            int a0 = tidx[4 * tt] * 3, a1 = tidx[4 * tt + 1] * 3,
                a2 = tidx[4 * tt + 2] * 3, a3 = tidx[4 * tt + 3] * 3;
            atomicAdd(&F[a0 + 0], dA.x * g);
            atomicAdd(&F[a0 + 1], dA.y * g);
            atomicAdd(&F[a0 + 2], dA.z * g);
            atomicAdd(&F[a1 + 0], dA.w * g);
            atomicAdd(&F[a1 + 1], dB.x * g);
            atomicAdd(&F[a1 + 2], dB.y * g);
            atomicAdd(&F[a2 + 0], dB.z * g);
            atomicAdd(&F[a2 + 1], dB.w * g);
            atomicAdd(&F[a2 + 2], dC.x * g);
            atomicAdd(&F[a3 + 0], dC.y * g);
            atomicAdd(&F[a3 + 1], dC.z * g);
            atomicAdd(&F[a3 + 2], dC.w * g);
        } else if (t < NBOND_TOT) {
            int ii = t - (NB + NA + NT);
            float ki = pim[ii];
            outE[OFF_EI + ii] = ki * (1.0f - c2i[s * NI + ii]);
            float g = -ki;
            const float4* dd = (const float4*)(dc2 + ((size_t)s * NI + ii) * 12);
            float4 dA = dd[0], dB = dd[1], dC = dd[2];
            int a0 = iidx[4 * ii] * 3, a1 = iidx[4 * ii + 1] * 3,
                a2 = iidx[4 * ii + 2] * 3, a3 = iidx[4 * ii + 3] * 3;
            atomicAdd(&F[a0 + 0], dA.x * g);
            atomicAdd(&F[a0 + 1], dA.y * g);
            atomicAdd(&F[a0 + 2], dA.z * g);
            atomicAdd(&F[a1 + 0], dA.w * g);
            atomicAdd(&F[a1 + 1], dB.x * g);
            atomicAdd(&F[a1 + 2], dB.y * g);
            atomicAdd(&F[a2 + 0], dB.z * g);
            atomicAdd(&F[a2 + 1], dB.w * g);
            atomicAdd(&F[a2 + 2], dC.x * g);
            atomicAdd(&F[a3 + 0], dC.y * g);
            atomicAdd(&F[a3 + 1], dC.z * g);
            atomicAdd(&F[a3 + 2], dC.w * g);
        }
        return;
    }

    // ---------------- vdw + charge path ----------------
    int chunk = blockIdx.y;
    for (int k = tid; k < N_ATOMS; k += VBLK) { fxy[k] = 0u; fz[k] = 0.0f; }
    __syncthreads();

    const int p0 = chunk * PPC;
    const float2* lvp   = (const float2*)(lv + (size_t)s * NV);
    const float4* dbase = (const float4*)(dlv + (size_t)s * NV * 6);

    for (int it = 0; it < VITER; ++it) {
        int p = p0 + it * VBLK + tid;
        if (p < p0 + PPC) {
            int v0 = 2 * p;
            float4 w0 = ws[v0];
            float4 w1 = ws[v0 + 1];
            float2 rr = lvp[p];
            float4 A = dbase[3 * (size_t)p];
            float4 B = dbase[3 * (size_t)p + 1];
            float4 C = dbase[3 * (size_t)p + 2];

            // --- v0 ---
            {
                float rinv  = __builtin_amdgcn_rcpf(rr.x);
                float r2inv = rinv * rinv;
                float r6inv = r2inv * r2inv * r2inv;
                float t     = w0.x * r6inv;
                float eps   = w0.y;
                float cc    = w0.z;
                outE[OFF_EV + v0] = eps * (t * t - 2.0f * t);
                outE[OFF_EC + v0] = cc * rinv;
                float fs    = 12.0f * eps * t * (1.0f - t) * rinv - cc * r2inv;
                unsigned pck = __float_as_uint(w0.w);
                int b0 = (int)(pck & 0xffffu);
                int b1 = (int)(pck >> 16);
                lds_pk_add(fxy, b0, A.x * fs, A.y * fs);
                atomicAdd(&fz[b0], A.z * fs);
                lds_pk_add(fxy, b1, A.w * fs, B.x * fs);
                atomicAdd(&fz[b1], B.y * fs);
            }
            // --- v1 ---
            {
                float rinv  = __builtin_amdgcn_rcpf(rr.y);
                float r2inv = rinv * rinv;
                float r6inv = r2inv * r2inv * r2inv;
                float t     = w1.x * r6inv;
                float eps   = w1.y;
                float cc    = w1.z;
                outE[OFF_EV + v0 + 1] = eps * (t * t - 2.0f * t);
                outE[OFF_EC + v0 + 1] = cc * rinv;
                float fs    = 12.0f * eps * t * (1.0f - t) * rinv - cc * r2inv;
                unsigned pck = __float_as_uint(w1.w);
                int b0 = (int)(pck & 0xffffu);
                int b1 = (int)(pck >> 16);
                lds_pk_add(fxy, b0, B.z * fs, B.w * fs);
                atomicAdd(&fz[b0], C.x * fs);
                lds_pk_add(fxy, b1, C.y * fs, C.z * fs);
                atomicAdd(&fz[b1], C.w * fs);
            }
        }
    }
    __syncthreads();

    // flush
    for (int k = tid; k < N_ATOMS; k += VBLK) {
        unsigned u = fxy[k];
        float z = fz[k];
        h2 hv = __builtin_bit_cast(h2, u);
        float x = (float)hv.x;
        float y = (float)hv.y;
        atomicAdd(&F[3 * k + 0], x);
        atomicAdd(&F[3 * k + 1], y);
        atomicAdd(&F[3 * k + 2], z);
    }
}

// ---------------------------------------------------------------------------
extern "C" void kernel_launch(void* const* d_in, const int* in_sizes, int n_in,
                              void* d_out, int out_size, void* d_ws, size_t ws_size,
                              hipStream_t stream) {
    const float* lb  = (const float*)d_in[0];
    const float* th  = (const float*)d_in[1];
    const float* lv  = (const float*)d_in[2];
    const float* sc  = (const float*)d_in[3];
    const float* c2i = (const float*)d_in[4];
    const float* v14 = (const float*)d_in[5];
    const float* q14 = (const float*)d_in[6];
    const float* pb  = (const float*)d_in[7];
    const float* pa  = (const float*)d_in[8];
    const float* pv  = (const float*)d_in[9];
    const float* pc  = (const float*)d_in[10];
    const float* pt  = (const float*)d_in[11];
    const float* pim = (const float*)d_in[12];
    const float* dlb = (const float*)d_in[13];
    const float* dth = (const float*)d_in[14];
    const float* dlv = (const float*)d_in[15];
    const float* dtt = (const float*)d_in[16];
    const float* dc2 = (const float*)d_in[17];
    const int* nb    = (const int*)d_in[18];
    const int* bidx  = (const int*)d_in[19];
    const int* aidx  = (const int*)d_in[20];
    const int* nbi   = (const int*)d_in[21];
    const int* tidx  = (const int*)d_in[22];
    const int* iidx  = (const int*)d_in[23];
    float* out = (float*)d_out;
    float4* ws = (float4*)d_ws;

    // 1) init + prep (independent, fused)
    {
        int total = NV;  // covers both roles
        init_prep_kernel<<<(total + 511) / 512, 512, 0, stream>>>(
            v14, q14, pv, pc, nb, nbi, ws, out);
    }
    // 2) bonded + vdw fused fat kernel
    {
        dim3 grid(NS, NCHUNK + NBBLK);
        fused_kernel<<<grid, VBLK, 0, stream>>>(
            lv, dlv, ws, lb, th, sc, c2i, pb, pa, pt, pim,
            dlb, dth, dtt, dc2, bidx, aidx, tidx, iidx, out);
    }
}